// Round 24
// baseline (130.165 us; speedup 1.0000x reference)
//
#include <hip/hip_runtime.h>
#include <hip/hip_bf16.h>
#include <math.h>

#define HSZ 1024
#define NHD 16
#define SEQ 2048
#define BSZ 2
#define MTOT (BSZ*SEQ)   // 4096

typedef __attribute__((ext_vector_type(4)))  float  f32x4;
typedef __attribute__((ext_vector_type(8)))  __bf16 bf16x8;

#define LOG2E 1.4426950408889634f

#if __has_builtin(__builtin_amdgcn_exp2f)
#define EXP2(x) __builtin_amdgcn_exp2f(x)
#else
#define EXP2(x) exp2f(x)
#endif

__device__ __forceinline__ unsigned short f2bf(float x) {
    union { float f; unsigned u; } v; v.f = x;
    unsigned r = v.u + 0x7FFFu + ((v.u >> 16) & 1u);
    return (unsigned short)(r >> 16);
}
__device__ __forceinline__ float bf2f(unsigned short u) {
    union { unsigned u; float f; } v; v.u = ((unsigned)u) << 16; return v.f;
}
__device__ __forceinline__ unsigned cvtpk(float lo, float hi) {
    unsigned r;
    asm("v_cvt_pk_bf16_f32 %0, %1, %2" : "=v"(r) : "v"(lo), "v"(hi));
    return r;
}

// ---------------------------------------------------------------------------
// fp32 -> bf16 bulk convert: hidden + Wq/Wk/Wv, plus mexp table
// ---------------------------------------------------------------------------
__global__ __launch_bounds__(256) void cvt_all(
    const float* __restrict__ h,  unsigned short* __restrict__ hd,
    const float* __restrict__ w0, unsigned short* __restrict__ w0d,
    const float* __restrict__ w1, unsigned short* __restrict__ w1d,
    const float* __restrict__ w2, unsigned short* __restrict__ w2d,
    const float* __restrict__ mask, unsigned short* __restrict__ mexpb)
{
    const int bid = blockIdx.x;
    if (bid >= 3584) {   // mexp path
        const int o = ((bid - 3584) * 256 + threadIdx.x) * 8;
        float4 a = *(const float4*)(mask + o);
        float4 b = *(const float4*)(mask + o + 4);
        uint4 v;
        v.x = f2bf(EXP2(a.x * LOG2E)) | ((unsigned)f2bf(EXP2(a.y * LOG2E)) << 16);
        v.y = f2bf(EXP2(a.z * LOG2E)) | ((unsigned)f2bf(EXP2(a.w * LOG2E)) << 16);
        v.z = f2bf(EXP2(b.x * LOG2E)) | ((unsigned)f2bf(EXP2(b.y * LOG2E)) << 16);
        v.w = f2bf(EXP2(b.z * LOG2E)) | ((unsigned)f2bf(EXP2(b.w * LOG2E)) << 16);
        *(uint4*)(mexpb + o) = v;
        return;
    }
    const float* s; unsigned short* d; int i;
    if (bid < 2048)      { s = h;  d = hd;  i = bid; }
    else if (bid < 2560) { s = w0; d = w0d; i = bid - 2048; }
    else if (bid < 3072) { s = w1; d = w1d; i = bid - 2560; }
    else                 { s = w2; d = w2d; i = bid - 3072; }
    const int o = (i * 256 + threadIdx.x) * 8;
    float4 a = *(const float4*)(s + o);
    float4 b = *(const float4*)(s + o + 4);
    uint4 v;
    v.x = f2bf(a.x) | ((unsigned)f2bf(a.y) << 16);
    v.y = f2bf(a.z) | ((unsigned)f2bf(a.w) << 16);
    v.z = f2bf(b.x) | ((unsigned)f2bf(b.y) << 16);
    v.w = f2bf(b.z) | ((unsigned)f2bf(b.w) << 16);
    *(uint4*)(d + o) = v;
}

// ---------------------------------------------------------------------------
// Fused QKV GEMM, bf16 MFMA — BM=64, BK=64, 2D XCD chunking, 2-barrier loop
// (round-22 verified, ~43 us). V^T store now UNSWIZZLED (V is read direct
// from global in attention; no LDS banks involved):
//   elem (d,kv) at tile byte d*128 + (kv&63)*2
// K keeps granule swizzle (kv&3)|((kv>>3)&1)<<2 for attn's permuted reads.
// ---------------------------------------------------------------------------
__global__ __launch_bounds__(256) void qkv_gemm(
    const unsigned short* __restrict__ hb,
    const unsigned short* __restrict__ wq,
    const unsigned short* __restrict__ wk,
    const unsigned short* __restrict__ wv,
    const float* __restrict__ bq, const float* __restrict__ bk,
    const float* __restrict__ bv, const unsigned short* __restrict__ mexpb,
    unsigned short* __restrict__ qo, char* __restrict__ ko,
    char* __restrict__ vo)
{
    __shared__ __align__(16) unsigned short As[64 * 64];    // 8 KB
    __shared__ __align__(16) unsigned short Bs[128 * 64];   // 16 KB

    const int t = threadIdx.x;
    const int w = t >> 6, l = t & 63, g = l >> 4, c = l & 15;
    const int lin = blockIdx.y * 24 + blockIdx.x;
    const int xcd = lin & 7, idx = lin >> 3;
    const int bn = (xcd & 1) * 12 + idx % 12;
    const int bm = (xcd >> 1) * 16 + idx / 12;
    const int which = bn >> 3;
    const int n0 = (bn & 7) << 7;
    const int m0 = bm << 6;
    const unsigned short* W = (which == 0) ? wq : (which == 1) ? wk : wv;
    const float* bb = (which == 0) ? bq : (which == 1) ? bk : bv;
    const float scale = (which == 0) ? 0.125f * LOG2E : 1.0f;
    const int wr = w >> 1, wc = w & 1;

    float mexpf[8];
    if (which == 2) {
        #pragma unroll
        for (int mi = 0; mi < 2; ++mi) {
            const int mrow = m0 + wr * 32 + mi * 16 + g * 4;
            const int bi = mrow >> 11, si = mrow & 2047;
            uint2 mv = *(const uint2*)(mexpb + bi * SEQ + si);
            mexpf[mi * 4 + 0] = bf2f((unsigned short)(mv.x & 0xFFFF));
            mexpf[mi * 4 + 1] = bf2f((unsigned short)(mv.x >> 16));
            mexpf[mi * 4 + 2] = bf2f((unsigned short)(mv.y & 0xFFFF));
            mexpf[mi * 4 + 3] = bf2f((unsigned short)(mv.y >> 16));
        }
    }

    f32x4 acc[2][4];
    #pragma unroll
    for (int mi = 0; mi < 2; ++mi)
        #pragma unroll
        for (int ni = 0; ni < 4; ++ni) acc[mi][ni] = {0.f, 0.f, 0.f, 0.f};

    const int srow = l >> 3;           // row-in-chunk 0..7
    const int sg   = (l & 7) ^ srow;   // pre-swizzled source granule

    for (int k0 = 0; k0 < HSZ; k0 += 64) {
        #pragma unroll
        for (int i2 = 0; i2 < 2; ++i2) {
            const int chunk = 2 * w + i2;
            const int row = chunk * 8 + srow;
            const char* ga = (const char*)hb +
                (((size_t)(m0 + row) << 10) + k0) * 2 + sg * 16;
            __builtin_amdgcn_global_load_lds(
                (const __attribute__((address_space(1))) unsigned*)ga,
                (__attribute__((address_space(3))) unsigned*)((char*)As + chunk * 1024),
                16, 0, 0);
        }
        #pragma unroll
        for (int i2 = 0; i2 < 4; ++i2) {
            const int chunk = 4 * w + i2;
            const int row = chunk * 8 + srow;
            const char* gb = (const char*)W +
                (((size_t)(n0 + row) << 10) + k0) * 2 + sg * 16;
            __builtin_amdgcn_global_load_lds(
                (const __attribute__((address_space(1))) unsigned*)gb,
                (__attribute__((address_space(3))) unsigned*)((char*)Bs + chunk * 1024),
                16, 0, 0);
        }
        __syncthreads();

        #pragma unroll
        for (int kk = 0; kk < 2; ++kk) {
            bf16x8 af[2], bfr[4];
            #pragma unroll
            for (int mi = 0; mi < 2; ++mi) {
                const int row = wr * 32 + mi * 16 + c;
                af[mi] = *(const bf16x8*)((const char*)As + row * 128
                             + ((kk * 4 + g) ^ (row & 7)) * 16);
            }
            #pragma unroll
            for (int ni = 0; ni < 4; ++ni) {
                const int row = wc * 64 + ni * 16 + c;
                bfr[ni] = *(const bf16x8*)((const char*)Bs + row * 128
                             + ((kk * 4 + g) ^ (row & 7)) * 16);
            }
            __builtin_amdgcn_s_setprio(1);
            #pragma unroll
            for (int mi = 0; mi < 2; ++mi)
                #pragma unroll
                for (int ni = 0; ni < 4; ++ni)
                    acc[mi][ni] = __builtin_amdgcn_mfma_f32_16x16x32_bf16(
                        af[mi], bfr[ni], acc[mi][ni], 0, 0, 0);
            __builtin_amdgcn_s_setprio(0);
        }
        __syncthreads();
    }

    #pragma unroll
    for (int ni = 0; ni < 4; ++ni) {
        const int ncol = n0 + wc * 64 + ni * 16 + c;
        const int hh = ncol >> 6, d = ncol & 63;
        const float bsc = bb[ncol] * scale;
        #pragma unroll
        for (int mi = 0; mi < 2; ++mi) {
            #pragma unroll
            for (int j = 0; j < 4; ++j) {
                const int mrow = m0 + wr * 32 + mi * 16 + g * 4 + j;
                const int bi = mrow >> 11, si = mrow & 2047;
                float vf = acc[mi][ni][j] * scale + bsc;
                if (which == 2) vf *= mexpf[mi * 4 + j];
                const unsigned short val = f2bf(vf);
                const size_t bhoff = (size_t)(bi * NHD + hh);
                if (which == 0) {
                    qo[((bhoff * SEQ + si) << 6) + d] = val;
                } else if (which == 1) {
                    const int kswz = ((si & 3) | (((si >> 3) & 1) << 2)) << 4;
                    char* p = ko + (bhoff << 18) + ((size_t)(si >> 6) << 13)
                            + ((si & 63) << 7) + ((d << 1) ^ kswz);
                    *(unsigned short*)p = val;
                } else {
                    char* p = vo + (bhoff << 18) + ((size_t)(si >> 6) << 13)
                            + (d << 7) + ((si & 63) << 1);      // unswizzled
                    *(unsigned short*)p = val;
                }
            }
        }
    }
}

// ---------------------------------------------------------------------------
// Flash attention: K staged in LDS (verified path); V read DIRECT FROM
// GLOBAL (L2-resident 512KB/head, contiguous 16B fragments from the plain
// tiled V^T layout, issued early so L2 latency hides under QK^T+exp).
// Halves the LDS-pipe traffic that bound the kernel at 52.5 us.
// kv-permuted QK^T, 2-phase counted sync, max-free softmax, mask folded
// into V, denominator via MFMA. LDS 16 KB.
// ---------------------------------------------------------------------------
__global__ __launch_bounds__(256) void attn_mfma(
    const unsigned short* __restrict__ qb, const char* __restrict__ kb,
    const char* __restrict__ vb, const unsigned short* __restrict__ mexpb,
    float* __restrict__ out)
{
    __shared__ __align__(16) char Kt[2][8192];   // total 16384 B

    const int t = threadIdx.x;
    const int w = t >> 6, l = t & 63, g = l >> 4, c = l & 15;
    const int qt = blockIdx.x, h = blockIdx.y, b = blockIdx.z;
    const int bh = b * NHD + h;
    const int q0 = qt * 128 + w * 32;

    const unsigned short* qp = qb + ((size_t)bh * SEQ + q0) * 64;
    const char* kbase = kb + ((size_t)bh << 18);
    const char* vbase = vb + ((size_t)bh << 18);
    const unsigned short* mep = mexpb + b * SEQ;

    bf16x8 qf[2][2];
    #pragma unroll
    for (int qh = 0; qh < 2; ++qh)
        #pragma unroll
        for (int p = 0; p < 2; ++p)
            qf[qh][p] = *(const bf16x8*)(qp + (qh * 16 + c) * 64 + p * 32 + g * 8);

    f32x4 o0[4], o1[4];
    #pragma unroll
    for (int tt = 0; tt < 4; ++tt) { o0[tt] = {0.f,0.f,0.f,0.f}; o1[tt] = {0.f,0.f,0.f,0.f}; }
    f32x4 ls0 = {0.f,0.f,0.f,0.f}, ls1 = {0.f,0.f,0.f,0.f};

    // stage K only: 2 gload_lds per wave per tile
    auto STAGE = [&](int tile, int buf) {
        const char* kg = kbase + tile * 8192 + w * 2048 + l * 16;
        #pragma unroll
        for (int i = 0; i < 2; ++i)
            __builtin_amdgcn_global_load_lds(
                (const __attribute__((address_space(1))) unsigned*)(kg + i * 1024),
                (__attribute__((address_space(3))) unsigned*)(&Kt[buf][w * 2048 + i * 1024]),
                16, 0, 0);
    };

    STAGE(0, 0);

    const int a_  = c >> 2, bb_ = c & 3;
    const int kswz = (bb_ | ((a_ & 1) << 2)) << 4;
    const int krow0 = (8 * a_ + bb_) * 128;

    int cur = 0;
    for (int kt = 0; kt < 32; ++kt) {
        const int kv0 = kt * 64;

        asm volatile("s_waitcnt vmcnt(0)" ::: "memory");
        __builtin_amdgcn_s_barrier();
        __builtin_amdgcn_sched_barrier(0);

        if (kt < 31) STAGE(kt + 1, cur ^ 1);

        // ---- V^T fragments DIRECT from global (contiguous 16B each),
        //      issued before QK so L2 latency hides under the MFMAs ----
        const char* vt = vbase + kt * 8192;
        bf16x8 vfr[4][2];
        #pragma unroll
        for (int tt = 0; tt < 4; ++tt)
            #pragma unroll
            for (int blk = 0; blk < 2; ++blk)
                vfr[tt][blk] = *(const bf16x8*)(vt + (tt * 16 + c) * 128
                                                + blk * 64 + g * 16);

        bf16x8 mf[2];
        #pragma unroll
        for (int blk = 0; blk < 2; ++blk)
            mf[blk] = *(const bf16x8*)(mep + kv0 + blk * 32 + g * 8);

        bf16x8 kfr[4][2];
        #pragma unroll
        for (int tt = 0; tt < 4; ++tt) {
            const int roff = krow0 + ((tt & 1) * 4 + (tt >> 1) * 32) * 128;
            #pragma unroll
            for (int p = 0; p < 2; ++p)
                kfr[tt][p] = *(const bf16x8*)(&Kt[cur][roff
                                 + ((p * 64 + g * 16) ^ kswz)]);
        }

        f32x4 s0[4], s1[4];
        #pragma unroll
        for (int t2 = 0; t2 < 4; ++t2) { s0[t2] = {0.f,0.f,0.f,0.f}; s1[t2] = {0.f,0.f,0.f,0.f}; }
        __builtin_amdgcn_s_setprio(1);
        #pragma unroll
        for (int t2 = 0; t2 < 4; ++t2) {
            s0[t2] = __builtin_amdgcn_mfma_f32_16x16x32_bf16(kfr[t2][0], qf[0][0], s0[t2], 0, 0, 0);
            s0[t2] = __builtin_amdgcn_mfma_f32_16x16x32_bf16(kfr[t2][1], qf[0][1], s0[t2], 0, 0, 0);
            s1[t2] = __builtin_amdgcn_mfma_f32_16x16x32_bf16(kfr[t2][0], qf[1][0], s1[t2], 0, 0, 0);
            s1[t2] = __builtin_amdgcn_mfma_f32_16x16x32_bf16(kfr[t2][1], qf[1][1], s1[t2], 0, 0, 0);
        }
        __builtin_amdgcn_s_setprio(0);

        #pragma unroll
        for (int t2 = 0; t2 < 4; ++t2) {
            s0[t2][0] = EXP2(s0[t2][0]); s0[t2][1] = EXP2(s0[t2][1]);
            s0[t2][2] = EXP2(s0[t2][2]); s0[t2][3] = EXP2(s0[t2][3]);
        }
        {
            bf16x8 pfr[2];
            #pragma unroll
            for (int blk = 0; blk < 2; ++blk) {
                uint4 tmp;
                tmp.x = cvtpk(s0[2*blk][0],   s0[2*blk][1]);
                tmp.y = cvtpk(s0[2*blk][2],   s0[2*blk][3]);
                tmp.z = cvtpk(s0[2*blk+1][0], s0[2*blk+1][1]);
                tmp.w = cvtpk(s0[2*blk+1][2], s0[2*blk+1][3]);
                pfr[blk] = *(bf16x8*)&tmp;
            }
            __builtin_amdgcn_s_setprio(1);
            #pragma unroll
            for (int blk = 0; blk < 2; ++blk)
                ls0 = __builtin_amdgcn_mfma_f32_16x16x32_bf16(mf[blk], pfr[blk], ls0, 0, 0, 0);
            #pragma unroll
            for (int tt = 0; tt < 4; ++tt)
                #pragma unroll
                for (int blk = 0; blk < 2; ++blk)
                    o0[tt] = __builtin_amdgcn_mfma_f32_16x16x32_bf16(vfr[tt][blk], pfr[blk], o0[tt], 0, 0, 0);
            __builtin_amdgcn_s_setprio(0);
        }

        #pragma unroll
        for (int t2 = 0; t2 < 4; ++t2) {
            s1[t2][0] = EXP2(s1[t2][0]); s1[t2][1] = EXP2(s1[t2][1]);
            s1[t2][2] = EXP2(s1[t2][2]); s1[t2][3] = EXP2(s1[t2][3]);
        }
        {
            bf16x8 pfr[2];
            #pragma unroll
            for (int blk = 0; blk < 2; ++blk) {
                uint4 tmp;
                tmp.x = cvtpk(s1[2*blk][0],   s1[2*blk][1]);
                tmp.y = cvtpk(s1[2*blk][2],   s1[2*blk][3]);
                tmp.z = cvtpk(s1[2*blk+1][0], s1[2*blk+1][1]);
                tmp.w = cvtpk(s1[2*blk+1][2], s1[2*blk+1][3]);
                pfr[blk] = *(bf16x8*)&tmp;
            }
            __builtin_amdgcn_s_setprio(1);
            #pragma unroll
            for (int blk = 0; blk < 2; ++blk)
                ls1 = __builtin_amdgcn_mfma_f32_16x16x32_bf16(mf[blk], pfr[blk], ls1, 0, 0, 0);
            #pragma unroll
            for (int tt = 0; tt < 4; ++tt)
                #pragma unroll
                for (int blk = 0; blk < 2; ++blk)
                    o1[tt] = __builtin_amdgcn_mfma_f32_16x16x32_bf16(vfr[tt][blk], pfr[blk], o1[tt], 0, 0, 0);
            __builtin_amdgcn_s_setprio(0);
        }

        cur ^= 1;
    }

    const float li0 = 1.f / ls0[0];
    const float li1 = 1.f / ls1[0];
    #pragma unroll
    for (int tt = 0; tt < 4; ++tt) {
        const size_t r0 = ((size_t)(b * SEQ + q0 + c) << 10) + h * 64 + 16 * tt + 4 * g;
        out[r0 + 0] = o0[tt][0] * li0;
        out[r0 + 1] = o0[tt][1] * li0;
        out[r0 + 2] = o0[tt][2] * li0;
        out[r0 + 3] = o0[tt][3] * li0;
        const size_t r1 = ((size_t)(b * SEQ + q0 + 16 + c) << 10) + h * 64 + 16 * tt + 4 * g;
        out[r1 + 0] = o1[tt][0] * li1;
        out[r1 + 1] = o1[tt][1] * li1;
        out[r1 + 2] = o1[tt][2] * li1;
        out[r1 + 3] = o1[tt][3] * li1;
    }
}

extern "C" void kernel_launch(void* const* d_in, const int* in_sizes, int n_in,
                              void* d_out, int out_size, void* d_ws, size_t ws_size,
                              hipStream_t stream) {
    const float* hid  = (const float*)d_in[0];
    const float* mask = (const float*)d_in[1];
    const float* Wq   = (const float*)d_in[2];
    const float* bq   = (const float*)d_in[3];
    const float* Wk   = (const float*)d_in[4];
    const float* bk   = (const float*)d_in[5];
    const float* Wv   = (const float*)d_in[6];
    const float* bv   = (const float*)d_in[7];
    float* out = (float*)d_out;

    char* ws = (char*)d_ws;
    unsigned short* qbf = (unsigned short*)(ws);                    // 8 MB
    char*           kbf = ws + 8388608;                             // 8 MB (tiled, kswz)
    char*           vbf = ws + 16777216;                            // 8 MB (V^T tiled plain, mexp-scaled)
    unsigned short* hbf = (unsigned short*)(ws + 25165824);         // 8 MB
    unsigned short* wqb = (unsigned short*)(ws + 33554432);         // 2 MB
    unsigned short* wkb = (unsigned short*)(ws + 35651584);         // 2 MB
    unsigned short* wvb = (unsigned short*)(ws + 37748736);         // 2 MB
    unsigned short* mxb = (unsigned short*)(ws + 39845888);         // 8 KB mexp table

    cvt_all<<<3586, 256, 0, stream>>>(hid, hbf, Wq, wqb, Wk, wkb, Wv, wvb,
                                      mask, mxb);
    qkv_gemm<<<dim3(24, 64), 256, 0, stream>>>(hbf, wqb, wkb, wvb,
                                               bq, bk, bv, mxb, qbf, kbf, vbf);
    attn_mfma<<<dim3(16, NHD, BSZ), 256, 0, stream>>>(qbf, kbf, vbf, mxb, out);
}

// Round 25
// 104.592 us; speedup vs baseline: 1.2445x; 1.2445x over previous
//
#include <hip/hip_runtime.h>
#include <hip/hip_bf16.h>
#include <math.h>

#define HSZ 1024
#define NHD 16
#define SEQ 2048
#define BSZ 2
#define MTOT (BSZ*SEQ)   // 4096

typedef __attribute__((ext_vector_type(4)))  float  f32x4;
typedef __attribute__((ext_vector_type(8)))  __bf16 bf16x8;

#define LOG2E 1.4426950408889634f

#if __has_builtin(__builtin_amdgcn_exp2f)
#define EXP2(x) __builtin_amdgcn_exp2f(x)
#else
#define EXP2(x) exp2f(x)
#endif

__device__ __forceinline__ unsigned short f2bf(float x) {
    union { float f; unsigned u; } v; v.f = x;
    unsigned r = v.u + 0x7FFFu + ((v.u >> 16) & 1u);
    return (unsigned short)(r >> 16);
}
__device__ __forceinline__ float bf2f(unsigned short u) {
    union { unsigned u; float f; } v; v.u = ((unsigned)u) << 16; return v.f;
}
__device__ __forceinline__ unsigned cvtpk(float lo, float hi) {
    unsigned r;
    asm("v_cvt_pk_bf16_f32 %0, %1, %2" : "=v"(r) : "v"(lo), "v"(hi));
    return r;
}

// ---------------------------------------------------------------------------
// fp32 -> bf16 bulk convert: hidden + Wq/Wk/Wv, plus mexp table
// ---------------------------------------------------------------------------
__global__ __launch_bounds__(256) void cvt_all(
    const float* __restrict__ h,  unsigned short* __restrict__ hd,
    const float* __restrict__ w0, unsigned short* __restrict__ w0d,
    const float* __restrict__ w1, unsigned short* __restrict__ w1d,
    const float* __restrict__ w2, unsigned short* __restrict__ w2d,
    const float* __restrict__ mask, unsigned short* __restrict__ mexpb)
{
    const int bid = blockIdx.x;
    if (bid >= 3584) {   // mexp path
        const int o = ((bid - 3584) * 256 + threadIdx.x) * 8;
        float4 a = *(const float4*)(mask + o);
        float4 b = *(const float4*)(mask + o + 4);
        uint4 v;
        v.x = f2bf(EXP2(a.x * LOG2E)) | ((unsigned)f2bf(EXP2(a.y * LOG2E)) << 16);
        v.y = f2bf(EXP2(a.z * LOG2E)) | ((unsigned)f2bf(EXP2(a.w * LOG2E)) << 16);
        v.z = f2bf(EXP2(b.x * LOG2E)) | ((unsigned)f2bf(EXP2(b.y * LOG2E)) << 16);
        v.w = f2bf(EXP2(b.z * LOG2E)) | ((unsigned)f2bf(EXP2(b.w * LOG2E)) << 16);
        *(uint4*)(mexpb + o) = v;
        return;
    }
    const float* s; unsigned short* d; int i;
    if (bid < 2048)      { s = h;  d = hd;  i = bid; }
    else if (bid < 2560) { s = w0; d = w0d; i = bid - 2048; }
    else if (bid < 3072) { s = w1; d = w1d; i = bid - 2560; }
    else                 { s = w2; d = w2d; i = bid - 3072; }
    const int o = (i * 256 + threadIdx.x) * 8;
    float4 a = *(const float4*)(s + o);
    float4 b = *(const float4*)(s + o + 4);
    uint4 v;
    v.x = f2bf(a.x) | ((unsigned)f2bf(a.y) << 16);
    v.y = f2bf(a.z) | ((unsigned)f2bf(a.w) << 16);
    v.z = f2bf(b.x) | ((unsigned)f2bf(b.y) << 16);
    v.w = f2bf(b.z) | ((unsigned)f2bf(b.w) << 16);
    *(uint4*)(d + o) = v;
}

// ---------------------------------------------------------------------------
// Fused QKV GEMM, bf16 MFMA — BM=64, BK=64, 2D XCD chunking, 2-barrier loop
// (verified best: ~43 us, FETCH 33 MB). 16 K-iters, each 16 MFMA + 12
// ds_read per wave. Staging: rows of 128B = 8 granules; lane l covers row
// chunk*8+(l>>3), src granule (l&7)^(l>>3); consumer granule (kk*4+g)^(row&7).
// K store granule swizzle (kv&3)|((kv>>3)&1)<<2 for attn's permuted reads;
// V^T store swizzled (((kv&63)<<1) ^ ((d&7)<<4)), mexp-scaled.
// ---------------------------------------------------------------------------
__global__ __launch_bounds__(256) void qkv_gemm(
    const unsigned short* __restrict__ hb,
    const unsigned short* __restrict__ wq,
    const unsigned short* __restrict__ wk,
    const unsigned short* __restrict__ wv,
    const float* __restrict__ bq, const float* __restrict__ bk,
    const float* __restrict__ bv, const unsigned short* __restrict__ mexpb,
    unsigned short* __restrict__ qo, char* __restrict__ ko,
    char* __restrict__ vo)
{
    __shared__ __align__(16) unsigned short As[64 * 64];    // 8 KB
    __shared__ __align__(16) unsigned short Bs[128 * 64];   // 16 KB

    const int t = threadIdx.x;
    const int w = t >> 6, l = t & 63, g = l >> 4, c = l & 15;
    const int lin = blockIdx.y * 24 + blockIdx.x;
    const int xcd = lin & 7, idx = lin >> 3;
    const int bn = (xcd & 1) * 12 + idx % 12;
    const int bm = (xcd >> 1) * 16 + idx / 12;
    const int which = bn >> 3;
    const int n0 = (bn & 7) << 7;
    const int m0 = bm << 6;
    const unsigned short* W = (which == 0) ? wq : (which == 1) ? wk : wv;
    const float* bb = (which == 0) ? bq : (which == 1) ? bk : bv;
    const float scale = (which == 0) ? 0.125f * LOG2E : 1.0f;
    const int wr = w >> 1, wc = w & 1;

    float mexpf[8];
    if (which == 2) {
        #pragma unroll
        for (int mi = 0; mi < 2; ++mi) {
            const int mrow = m0 + wr * 32 + mi * 16 + g * 4;
            const int bi = mrow >> 11, si = mrow & 2047;
            uint2 mv = *(const uint2*)(mexpb + bi * SEQ + si);
            mexpf[mi * 4 + 0] = bf2f((unsigned short)(mv.x & 0xFFFF));
            mexpf[mi * 4 + 1] = bf2f((unsigned short)(mv.x >> 16));
            mexpf[mi * 4 + 2] = bf2f((unsigned short)(mv.y & 0xFFFF));
            mexpf[mi * 4 + 3] = bf2f((unsigned short)(mv.y >> 16));
        }
    }

    f32x4 acc[2][4];
    #pragma unroll
    for (int mi = 0; mi < 2; ++mi)
        #pragma unroll
        for (int ni = 0; ni < 4; ++ni) acc[mi][ni] = {0.f, 0.f, 0.f, 0.f};

    const int srow = l >> 3;           // row-in-chunk 0..7
    const int sg   = (l & 7) ^ srow;   // pre-swizzled source granule (0..7)

    for (int k0 = 0; k0 < HSZ; k0 += 64) {
        // A: 8 chunks of 1KB (8 rows each); wave w stages chunks 2w, 2w+1
        #pragma unroll
        for (int i2 = 0; i2 < 2; ++i2) {
            const int chunk = 2 * w + i2;
            const int row = chunk * 8 + srow;
            const char* ga = (const char*)hb +
                (((size_t)(m0 + row) << 10) + k0) * 2 + sg * 16;
            __builtin_amdgcn_global_load_lds(
                (const __attribute__((address_space(1))) unsigned*)ga,
                (__attribute__((address_space(3))) unsigned*)((char*)As + chunk * 1024),
                16, 0, 0);
        }
        // B: 16 chunks; wave w stages chunks 4w..4w+3
        #pragma unroll
        for (int i2 = 0; i2 < 4; ++i2) {
            const int chunk = 4 * w + i2;
            const int row = chunk * 8 + srow;
            const char* gb = (const char*)W +
                (((size_t)(n0 + row) << 10) + k0) * 2 + sg * 16;
            __builtin_amdgcn_global_load_lds(
                (const __attribute__((address_space(1))) unsigned*)gb,
                (__attribute__((address_space(3))) unsigned*)((char*)Bs + chunk * 1024),
                16, 0, 0);
        }
        __syncthreads();

        #pragma unroll
        for (int kk = 0; kk < 2; ++kk) {
            bf16x8 af[2], bfr[4];
            #pragma unroll
            for (int mi = 0; mi < 2; ++mi) {
                const int row = wr * 32 + mi * 16 + c;
                af[mi] = *(const bf16x8*)((const char*)As + row * 128
                             + ((kk * 4 + g) ^ (row & 7)) * 16);
            }
            #pragma unroll
            for (int ni = 0; ni < 4; ++ni) {
                const int row = wc * 64 + ni * 16 + c;
                bfr[ni] = *(const bf16x8*)((const char*)Bs + row * 128
                             + ((kk * 4 + g) ^ (row & 7)) * 16);
            }
            __builtin_amdgcn_s_setprio(1);
            #pragma unroll
            for (int mi = 0; mi < 2; ++mi)
                #pragma unroll
                for (int ni = 0; ni < 4; ++ni)
                    acc[mi][ni] = __builtin_amdgcn_mfma_f32_16x16x32_bf16(
                        af[mi], bfr[ni], acc[mi][ni], 0, 0, 0);
            __builtin_amdgcn_s_setprio(0);
        }
        __syncthreads();
    }

    #pragma unroll
    for (int ni = 0; ni < 4; ++ni) {
        const int ncol = n0 + wc * 64 + ni * 16 + c;
        const int hh = ncol >> 6, d = ncol & 63;
        const float bsc = bb[ncol] * scale;
        #pragma unroll
        for (int mi = 0; mi < 2; ++mi) {
            #pragma unroll
            for (int j = 0; j < 4; ++j) {
                const int mrow = m0 + wr * 32 + mi * 16 + g * 4 + j;
                const int bi = mrow >> 11, si = mrow & 2047;
                float vf = acc[mi][ni][j] * scale + bsc;
                if (which == 2) vf *= mexpf[mi * 4 + j];
                const unsigned short val = f2bf(vf);
                const size_t bhoff = (size_t)(bi * NHD + hh);
                if (which == 0) {
                    qo[((bhoff * SEQ + si) << 6) + d] = val;
                } else if (which == 1) {
                    const int kswz = ((si & 3) | (((si >> 3) & 1) << 2)) << 4;
                    char* p = ko + (bhoff << 18) + ((size_t)(si >> 6) << 13)
                            + ((si & 63) << 7) + ((d << 1) ^ kswz);
                    *(unsigned short*)p = val;
                } else {
                    char* p = vo + (bhoff << 18) + ((size_t)(si >> 6) << 13)
                            + (d << 7) + (((si & 63) << 1) ^ ((d & 7) << 4));
                    *(unsigned short*)p = val;
                }
            }
        }
    }
}

// ---------------------------------------------------------------------------
// Flash attention (verified best, ~52.5 us): kv-permuted QK^T (no P LDS
// round-trip, zero bank conflicts), 2-phase counted sync, max-free softmax,
// mask folded into V, denominator via MFMA. LDS 32 KB.
// ---------------------------------------------------------------------------
__global__ __launch_bounds__(256) void attn_mfma(
    const unsigned short* __restrict__ qb, const char* __restrict__ kb,
    const char* __restrict__ vb, const unsigned short* __restrict__ mexpb,
    float* __restrict__ out)
{
    __shared__ __align__(16) char Kt[2][8192];
    __shared__ __align__(16) char Vt[2][8192];   // total 32768 B

    const int t = threadIdx.x;
    const int w = t >> 6, l = t & 63, g = l >> 4, c = l & 15;
    const int qt = blockIdx.x, h = blockIdx.y, b = blockIdx.z;
    const int bh = b * NHD + h;
    const int q0 = qt * 128 + w * 32;

    const unsigned short* qp = qb + ((size_t)bh * SEQ + q0) * 64;
    const char* kbase = kb + ((size_t)bh << 18);
    const char* vbase = vb + ((size_t)bh << 18);
    const unsigned short* mep = mexpb + b * SEQ;

    bf16x8 qf[2][2];
    #pragma unroll
    for (int qh = 0; qh < 2; ++qh)
        #pragma unroll
        for (int p = 0; p < 2; ++p)
            qf[qh][p] = *(const bf16x8*)(qp + (qh * 16 + c) * 64 + p * 32 + g * 8);

    f32x4 o0[4], o1[4];
    #pragma unroll
    for (int tt = 0; tt < 4; ++tt) { o0[tt] = {0.f,0.f,0.f,0.f}; o1[tt] = {0.f,0.f,0.f,0.f}; }
    f32x4 ls0 = {0.f,0.f,0.f,0.f}, ls1 = {0.f,0.f,0.f,0.f};

    auto STAGE = [&](int tile, int buf) {
        const char* kg = kbase + tile * 8192 + w * 2048 + l * 16;
        const char* vg = vbase + tile * 8192 + w * 2048 + l * 16;
        #pragma unroll
        for (int i = 0; i < 2; ++i) {
            __builtin_amdgcn_global_load_lds(
                (const __attribute__((address_space(1))) unsigned*)(kg + i * 1024),
                (__attribute__((address_space(3))) unsigned*)(&Kt[buf][w * 2048 + i * 1024]),
                16, 0, 0);
            __builtin_amdgcn_global_load_lds(
                (const __attribute__((address_space(1))) unsigned*)(vg + i * 1024),
                (__attribute__((address_space(3))) unsigned*)(&Vt[buf][w * 2048 + i * 1024]),
                16, 0, 0);
        }
    };

    STAGE(0, 0);

    const int a_  = c >> 2, bb_ = c & 3;
    const int kswz = (bb_ | ((a_ & 1) << 2)) << 4;
    const int krow0 = (8 * a_ + bb_) * 128;

    int cur = 0;
    for (int kt = 0; kt < 32; ++kt) {
        const int kv0 = kt * 64;

        asm volatile("s_waitcnt vmcnt(0)" ::: "memory");
        __builtin_amdgcn_s_barrier();
        __builtin_amdgcn_sched_barrier(0);

        if (kt < 31) STAGE(kt + 1, cur ^ 1);

        bf16x8 mf[2];
        #pragma unroll
        for (int blk = 0; blk < 2; ++blk)
            mf[blk] = *(const bf16x8*)(mep + kv0 + blk * 32 + g * 8);

        bf16x8 kfr[4][2];
        #pragma unroll
        for (int tt = 0; tt < 4; ++tt) {
            const int roff = krow0 + ((tt & 1) * 4 + (tt >> 1) * 32) * 128;
            #pragma unroll
            for (int p = 0; p < 2; ++p)
                kfr[tt][p] = *(const bf16x8*)(&Kt[cur][roff
                                 + ((p * 64 + g * 16) ^ kswz)]);
        }

        f32x4 s0[4], s1[4];
        #pragma unroll
        for (int t2 = 0; t2 < 4; ++t2) { s0[t2] = {0.f,0.f,0.f,0.f}; s1[t2] = {0.f,0.f,0.f,0.f}; }
        __builtin_amdgcn_s_setprio(1);
        #pragma unroll
        for (int t2 = 0; t2 < 4; ++t2) {
            s0[t2] = __builtin_amdgcn_mfma_f32_16x16x32_bf16(kfr[t2][0], qf[0][0], s0[t2], 0, 0, 0);
            s0[t2] = __builtin_amdgcn_mfma_f32_16x16x32_bf16(kfr[t2][1], qf[0][1], s0[t2], 0, 0, 0);
            s1[t2] = __builtin_amdgcn_mfma_f32_16x16x32_bf16(kfr[t2][0], qf[1][0], s1[t2], 0, 0, 0);
            s1[t2] = __builtin_amdgcn_mfma_f32_16x16x32_bf16(kfr[t2][1], qf[1][1], s1[t2], 0, 0, 0);
        }
        __builtin_amdgcn_s_setprio(0);

        bf16x8 vfr[4][2];
        #pragma unroll
        for (int tt = 0; tt < 4; ++tt)
            #pragma unroll
            for (int blk = 0; blk < 2; ++blk)
                vfr[tt][blk] = *(const bf16x8*)(&Vt[cur][(tt * 16 + c) * 128
                                     + ((blk * 64 + g * 16) ^ ((c & 7) << 4))]);

        #pragma unroll
        for (int t2 = 0; t2 < 4; ++t2) {
            s0[t2][0] = EXP2(s0[t2][0]); s0[t2][1] = EXP2(s0[t2][1]);
            s0[t2][2] = EXP2(s0[t2][2]); s0[t2][3] = EXP2(s0[t2][3]);
        }
        {
            bf16x8 pfr[2];
            #pragma unroll
            for (int blk = 0; blk < 2; ++blk) {
                uint4 tmp;
                tmp.x = cvtpk(s0[2*blk][0],   s0[2*blk][1]);
                tmp.y = cvtpk(s0[2*blk][2],   s0[2*blk][3]);
                tmp.z = cvtpk(s0[2*blk+1][0], s0[2*blk+1][1]);
                tmp.w = cvtpk(s0[2*blk+1][2], s0[2*blk+1][3]);
                pfr[blk] = *(bf16x8*)&tmp;
            }
            __builtin_amdgcn_s_setprio(1);
            #pragma unroll
            for (int blk = 0; blk < 2; ++blk)
                ls0 = __builtin_amdgcn_mfma_f32_16x16x32_bf16(mf[blk], pfr[blk], ls0, 0, 0, 0);
            #pragma unroll
            for (int tt = 0; tt < 4; ++tt)
                #pragma unroll
                for (int blk = 0; blk < 2; ++blk)
                    o0[tt] = __builtin_amdgcn_mfma_f32_16x16x32_bf16(vfr[tt][blk], pfr[blk], o0[tt], 0, 0, 0);
            __builtin_amdgcn_s_setprio(0);
        }

        #pragma unroll
        for (int t2 = 0; t2 < 4; ++t2) {
            s1[t2][0] = EXP2(s1[t2][0]); s1[t2][1] = EXP2(s1[t2][1]);
            s1[t2][2] = EXP2(s1[t2][2]); s1[t2][3] = EXP2(s1[t2][3]);
        }
        {
            bf16x8 pfr[2];
            #pragma unroll
            for (int blk = 0; blk < 2; ++blk) {
                uint4 tmp;
                tmp.x = cvtpk(s1[2*blk][0],   s1[2*blk][1]);
                tmp.y = cvtpk(s1[2*blk][2],   s1[2*blk][3]);
                tmp.z = cvtpk(s1[2*blk+1][0], s1[2*blk+1][1]);
                tmp.w = cvtpk(s1[2*blk+1][2], s1[2*blk+1][3]);
                pfr[blk] = *(bf16x8*)&tmp;
            }
            __builtin_amdgcn_s_setprio(1);
            #pragma unroll
            for (int blk = 0; blk < 2; ++blk)
                ls1 = __builtin_amdgcn_mfma_f32_16x16x32_bf16(mf[blk], pfr[blk], ls1, 0, 0, 0);
            #pragma unroll
            for (int tt = 0; tt < 4; ++tt)
                #pragma unroll
                for (int blk = 0; blk < 2; ++blk)
                    o1[tt] = __builtin_amdgcn_mfma_f32_16x16x32_bf16(vfr[tt][blk], pfr[blk], o1[tt], 0, 0, 0);
            __builtin_amdgcn_s_setprio(0);
        }

        cur ^= 1;
    }

    const float li0 = 1.f / ls0[0];
    const float li1 = 1.f / ls1[0];
    #pragma unroll
    for (int tt = 0; tt < 4; ++tt) {
        const size_t r0 = ((size_t)(b * SEQ + q0 + c) << 10) + h * 64 + 16 * tt + 4 * g;
        out[r0 + 0] = o0[tt][0] * li0;
        out[r0 + 1] = o0[tt][1] * li0;
        out[r0 + 2] = o0[tt][2] * li0;
        out[r0 + 3] = o0[tt][3] * li0;
        const size_t r1 = ((size_t)(b * SEQ + q0 + 16 + c) << 10) + h * 64 + 16 * tt + 4 * g;
        out[r1 + 0] = o1[tt][0] * li1;
        out[r1 + 1] = o1[tt][1] * li1;
        out[r1 + 2] = o1[tt][2] * li1;
        out[r1 + 3] = o1[tt][3] * li1;
    }
}

extern "C" void kernel_launch(void* const* d_in, const int* in_sizes, int n_in,
                              void* d_out, int out_size, void* d_ws, size_t ws_size,
                              hipStream_t stream) {
    const float* hid  = (const float*)d_in[0];
    const float* mask = (const float*)d_in[1];
    const float* Wq   = (const float*)d_in[2];
    const float* bq   = (const float*)d_in[3];
    const float* Wk   = (const float*)d_in[4];
    const float* bk   = (const float*)d_in[5];
    const float* Wv   = (const float*)d_in[6];
    const float* bv   = (const float*)d_in[7];
    float* out = (float*)d_out;

    char* ws = (char*)d_ws;
    unsigned short* qbf = (unsigned short*)(ws);                    // 8 MB
    char*           kbf = ws + 8388608;                             // 8 MB (tiled, kswz)
    char*           vbf = ws + 16777216;                            // 8 MB (V^T tiled+swz, mexp-scaled)
    unsigned short* hbf = (unsigned short*)(ws + 25165824);         // 8 MB
    unsigned short* wqb = (unsigned short*)(ws + 33554432);         // 2 MB
    unsigned short* wkb = (unsigned short*)(ws + 35651584);         // 2 MB
    unsigned short* wvb = (unsigned short*)(ws + 37748736);         // 2 MB
    unsigned short* mxb = (unsigned short*)(ws + 39845888);         // 8 KB mexp table

    cvt_all<<<3586, 256, 0, stream>>>(hid, hbf, Wq, wqb, Wk, wkb, Wv, wvb,
                                      mask, mxb);
    qkv_gemm<<<dim3(24, 64), 256, 0, stream>>>(hbf, wqb, wkb, wvb,
                                               bq, bk, bv, mxb, qbf, kbf, vbf);
    attn_mfma<<<dim3(16, NHD, BSZ), 256, 0, stream>>>(qbf, kbf, vbf, mxb, out);
}